// Round 24
// baseline (101.079 us; speedup 1.0000x reference)
//
#include <hip/hip_runtime.h>
#include <hip/hip_bf16.h>
#include <stdint.h>
#include <stddef.h>

#define BATCH 4
#define SEQ   2048
#define DM    512
#define NST   64
#define LN_EPS 1e-5f
#define NCH   32    // 32 chunks of 64
#define KDIM  192   // 64 x-taps + 128 carry (re,im interleaved)

typedef __attribute__((ext_vector_type(8))) short short8;
typedef __attribute__((ext_vector_type(4))) float f32x4;

__device__ __forceinline__ ushort f2bf(float f) {
    __hip_bfloat16 h = __float2bfloat16(f);
    return *(ushort*)&h;
}
__device__ __forceinline__ float bf2f(ushort u) {
    __hip_bfloat16 h = *(__hip_bfloat16*)&u;
    return __bfloat162float(h);
}

// ---------------- k_prep: fused  x-transpose | W-convert | M+G build ----------------
// blocks [0,2048):    x[b][l][d] f32 -> xT[d][b][l] bf16
// blocks [2048,3072): W->bf16
// blocks [3072,3200): per-d FIR/carry matrix M[64][192] bf16  +  G[128][64] bf16 + eA^64
__global__ __launch_bounds__(256) void k_prep(
    const float* __restrict__ x,
    const float* __restrict__ logA, const float* __restrict__ Aim,
    const float* __restrict__ Bp, const float* __restrict__ Cp,
    const float* __restrict__ W,
    __hip_bfloat16* __restrict__ xT,
    __hip_bfloat16* __restrict__ Wbf, __hip_bfloat16* __restrict__ Mt,
    __hip_bfloat16* __restrict__ Gt, float2* __restrict__ e64)
{
    __shared__ float smem[64][33];
    const int tid = threadIdx.x;
    const int bid = blockIdx.x;

    if (bid < 2048) {
        const int dt = bid & 15, lt = (bid >> 4) & 31, b = bid >> 9;
        const int l0 = lt * 64, d0 = dt * 32;
        const int dd = tid & 31, lr = tid >> 5;
        #pragma unroll
        for (int it = 0; it < 8; ++it) {
            int ll = it * 8 + lr;
            smem[ll][dd] = x[((size_t)b * SEQ + l0 + ll) * DM + d0 + dd];
        }
        __syncthreads();
        const int dw = tid >> 3, lg = (tid & 7) * 8;
        ushort pk[8];
        #pragma unroll
        for (int i = 0; i < 8; ++i) pk[i] = f2bf(smem[lg + i][dw]);
        *(short8*)&xT[((size_t)(d0 + dw) * BATCH + b) * SEQ + l0 + lg] = *(short8*)pk;
    } else if (bid < 3072) {
        int i = (bid - 2048) * 256 + tid;
        if (i < DM * DM) Wbf[i] = __float2bfloat16(W[i]);
    } else {
        // M[i][j] = K[j-i] (j>=i else 0); M[i][64+2s] = Re(eA_s^(64-i)); M[i][65+2s] = -Im
        // G[2s][t] = Re(eA^t CB), G[2s+1][t] = Im(eA^t CB); e64 = eA^64
        float (*Klds)[64] = (float(*)[64])smem;
        const int w = tid >> 6, lane = tid & 63;
        const int d = (bid - 3072) * 4 + w;
        const int i = d * NST + lane;
        float aa  = expf(logA[i]);
        float wim = Aim[i];
        float mag = expf(-aa);
        float er = mag * cosf(wim), ei = mag * sinf(wim);
        float Br = Bp[2*i], Bi = Bp[2*i+1];
        float Cr = Cp[2*i], Ci = Cp[2*i+1];
        float pr = Cr*Br + Ci*Bi;                 // CB * eA^t (t=0)
        float pi = Cr*Bi - Ci*Br;
        float ar = 1.f, ai = 0.f;                 // eA^t
        __hip_bfloat16* Md = Mt + (size_t)d * 64 * KDIM;
        __hip_bfloat16* Gr = Gt + ((size_t)d * 128 + 2 * lane) * 64;       // re row
        __hip_bfloat16* Gi = Gt + ((size_t)d * 128 + 2 * lane + 1) * 64;   // im row
        for (int tb = 0; tb < 8; ++tb) {
            ushort bufR[8], bufI[8];
            #pragma unroll
            for (int tt = 0; tt < 8; ++tt) {
                const int t = tb * 8 + tt;
                float kv = pr;
                #pragma unroll
                for (int mask = 1; mask < 64; mask <<= 1) kv += __shfl_xor(kv, mask);
                if (lane == 0) Klds[w][t] = kv;
                bufR[tt] = f2bf(pr);              // G row values at k=t
                bufI[tt] = f2bf(pi);
                float npr = er*pr - ei*pi, npi = er*pi + ei*pr;  pr = npr; pi = npi;
                float nar = er*ar - ei*ai, nai = er*ai + ei*ar;  ar = nar; ai = nai;
                uint u = (uint)f2bf(ar) | ((uint)f2bf(-ai) << 16);
                *(uint*)&Md[(63 - t) * KDIM + 64 + 2 * lane] = u;   // row 64-(t+1)
            }
            *(short8*)&Gr[tb * 8] = *(short8*)bufR;
            *(short8*)&Gi[tb * 8] = *(short8*)bufI;
        }
        e64[(size_t)d * NST + lane] = make_float2(ar, ai);   // eA^64
        __syncthreads();
        for (int r = 0; r < 64; ++r) {
            float v = (lane >= r) ? Klds[w][lane - r] : 0.f;
            Md[r * KDIM + lane] = __float2bfloat16(v);
        }
    }
}

// ---------------- k_ssm: merged scanU + gemmY (per-d block; carries never leave LDS) ----------------
__global__ __launch_bounds__(256) void k_ssm(
    const __hip_bfloat16* __restrict__ Gt, const __hip_bfloat16* __restrict__ Mt,
    const __hip_bfloat16* __restrict__ xT, const float2* __restrict__ e64,
    const float* __restrict__ Dp, __hip_bfloat16* __restrict__ yT)
{
    __shared__ short Zs[128 * 24 * 8];            // 48K persistent: x chunks 0-7, carry chunks 8-23
    __shared__ __align__(16) char Rgn[16384 + 128 * 129 * 4];   // union: {Gs 16K + Us 64.5K} / {Ms 24K}
    short* Gs = (short*)Rgn;
    float (*Us)[129] = (float(*)[129])(Rgn + 16384);
    short* Ms = (short*)Rgn;

    const int tid = threadIdx.x;
    const int d = blockIdx.x;
    const int w = tid >> 6, lane = tid & 63;
    const int q = lane >> 4, n = lane & 15;

    // ---- stage Gs (128 rows x 8 chunks) and Zs x-part (128 cols x 8 chunks) ----
    {
        const short* Gg = (const short*)(Gt + (size_t)d * 128 * 64);
        #pragma unroll
        for (int it = 0; it < 4; ++it) {
            int Gc = it * 256 + tid;
            int row = Gc >> 3, c = Gc & 7;
            int cs = c ^ (row & 7);
            *(short8*)&Gs[(row * 8 + cs) * 8] = *(const short8*)&Gg[Gc * 8];
        }
        #pragma unroll
        for (int it = 0; it < 4; ++it) {
            int id = it * 256 + tid;
            int col = id >> 3, ck = id & 7;
            int bb = col >> 5, ch = col & 31;
            short8 v = *(const short8*)&xT[((size_t)d * BATCH + bb) * SEQ + ch * 64 + ck * 8];
            int cs = ck ^ (col & 7);
            *(short8*)&Zs[(col * 24 + cs) * 8] = v;
        }
    }
    __syncthreads();

    // ---- phase 1: U = G * X ----
    {
        f32x4 acc[2][8];
        #pragma unroll
        for (int rt = 0; rt < 2; ++rt)
            #pragma unroll
            for (int nf = 0; nf < 8; ++nf)
                #pragma unroll
                for (int k = 0; k < 4; ++k) acc[rt][nf][k] = 0.f;

        #pragma unroll
        for (int rt = 0; rt < 2; ++rt) {
            const int arow = w * 32 + rt * 16 + n;
            #pragma unroll
            for (int kt = 0; kt < 2; ++kt) {
                int c = kt * 4 + q;
                int csa = c ^ (arow & 7);
                short8 af = *(const short8*)&Gs[(arow * 8 + csa) * 8];
                #pragma unroll
                for (int nf = 0; nf < 8; ++nf) {
                    int col = nf * 16 + n;
                    int csb = c ^ (col & 7);
                    short8 bf = *(const short8*)&Zs[(col * 24 + csb) * 8];
                    acc[rt][nf] = __builtin_amdgcn_mfma_f32_16x16x32_bf16(af, bf, acc[rt][nf], 0, 0, 0);
                }
            }
        }
        #pragma unroll
        for (int rt = 0; rt < 2; ++rt) {
            const int r0w = w * 32 + rt * 16 + q * 4;
            #pragma unroll
            for (int nf = 0; nf < 8; ++nf) {
                int col = nf * 16 + n;
                #pragma unroll
                for (int r = 0; r < 4; ++r) Us[r0w + r][col] = acc[rt][nf][r];
            }
        }
    }
    __syncthreads();

    // ---- phase 2: carry combine, bf16 results straight into Zs carry chunks ----
    {
        const int bb = tid >> 6, s = tid & 63;
        const int st = s >> 2, so = (s & 3) * 2;        // chunk st, short offset within 16B
        float2 a64 = e64[(size_t)d * NST + s];
        const float er = a64.x, ei = a64.y;
        {
            int col = bb * 32 + 31;
            int c = 8 + st, cs = (c & ~7) | ((c & 7) ^ (col & 7));
            *(uint*)&Zs[(col * 24 + cs) * 8 + so] = 0u;
        }
        float gr = Us[2 * s][bb * 32 + 31], gi = Us[2 * s + 1][bb * 32 + 31];
        {
            int col = bb * 32 + 30;
            int c = 8 + st, cs = (c & ~7) | ((c & 7) ^ (col & 7));
            *(uint*)&Zs[(col * 24 + cs) * 8 + so] = (uint)f2bf(gr) | ((uint)f2bf(gi) << 16);
        }
        for (int ch = 30; ch >= 1; --ch) {
            float ur = Us[2 * s][bb * 32 + ch], ui = Us[2 * s + 1][bb * 32 + ch];
            float nr = ur + er * gr - ei * gi;
            float ni = ui + er * gi + ei * gr;
            gr = nr; gi = ni;
            int col = bb * 32 + ch - 1;
            int c = 8 + st, cs = (c & ~7) | ((c & 7) ^ (col & 7));
            *(uint*)&Zs[(col * 24 + cs) * 8 + so] = (uint)f2bf(gr) | ((uint)f2bf(gi) << 16);
        }
    }
    __syncthreads();

    // ---- stage Ms into the union region (Gs/Us dead now) ----
    {
        const short* Mg = (const short*)(Mt + (size_t)d * 64 * KDIM);
        #pragma unroll
        for (int it = 0; it < 6; ++it) {
            int G = it * 256 + tid;
            int row = G / 24, c = G % 24;
            int cs = (c & ~7) | ((c & 7) ^ (row & 7));
            *(short8*)&Ms[(row * 24 + cs) * 8] = *(const short8*)&Mg[G * 8];
        }
    }
    __syncthreads();

    // ---- phase 3: y = M * Z, + D*x, store yT ----
    f32x4 acc[8];
    #pragma unroll
    for (int nf = 0; nf < 8; ++nf)
        #pragma unroll
        for (int k = 0; k < 4; ++k) acc[nf][k] = 0.f;

    const int arow = w * 16 + n;
    #pragma unroll
    for (int kt = 0; kt < 6; ++kt) {
        int c = kt * 4 + q;
        int csa = (c & ~7) | ((c & 7) ^ (arow & 7));
        short8 af = *(const short8*)&Ms[(arow * 24 + csa) * 8];
        #pragma unroll
        for (int nf = 0; nf < 8; ++nf) {
            int col = nf * 16 + n;
            int csb = (c & ~7) | ((c & 7) ^ (col & 7));
            short8 bfr = *(const short8*)&Zs[(col * 24 + csb) * 8];
            acc[nf] = __builtin_amdgcn_mfma_f32_16x16x32_bf16(af, bfr, acc[nf], 0, 0, 0);
        }
    }

    const float Dd = Dp[d];
    const int i0 = w * 16 + q * 4;
    #pragma unroll
    for (int nf = 0; nf < 8; ++nf) {
        int col = nf * 16 + n;
        int bb = col >> 5, ch = col & 31;
        int cx = (i0 >> 3) ^ (col & 7);
        const ushort* zp = (const ushort*)&Zs[(col * 24 + cx) * 8 + (i0 & 7)];
        ushort o[4];
        #pragma unroll
        for (int r = 0; r < 4; ++r)
            o[r] = f2bf(acc[nf][r] + Dd * bf2f(zp[r]));
        *(uint2*)&yT[((size_t)d * BATCH + bb) * SEQ + ch * 64 + i0] = *(uint2*)o;
    }
}

// ---------------- k_gemm_ln v14: A panel direct from yT + dbuf reg-staged B (round-20 proven) ----------------
__global__ __launch_bounds__(512) void k_gemm_ln(
    const __hip_bfloat16* __restrict__ yT, const __hip_bfloat16* __restrict__ Wbf,
    const float* __restrict__ x, const float* __restrict__ bout,
    const float* __restrict__ gamma, const float* __restrict__ beta,
    float* __restrict__ out)
{
    __shared__ short Af[32][520];     // full A panel [l][kd]; stride 520
    __shared__ short Bs[512][32];     // W tile [o][k], 16B-chunk XOR swizzle (validated)
    __shared__ float red[8][32][2];
    __shared__ float stats[32][2];

    const int tid  = threadIdx.x;
    const int w    = tid >> 6;
    const int lane = tid & 63;
    const int q    = lane >> 4;
    const int m    = lane & 15;
    const int r0   = blockIdx.x * 32;
    const int bq   = r0 >> 11;           // batch index (r0 32-aligned, no straddle)
    const int l0   = r0 & 2047;

    // ---- one-time A panel from yT[d][b][l]: thread (kdb, lg) reads 8 overlapped uint2 ----
    {
        const int kdb = tid >> 3, lg = (tid & 7) * 4;
        uint2 u[8];
        #pragma unroll
        for (int j = 0; j < 8; ++j)
            u[j] = *(const uint2*)&yT[((size_t)(j * 64 + kdb) * BATCH + bq) * SEQ + l0 + lg];
        #pragma unroll
        for (int j = 0; j < 8; ++j) {
            int kd = j * 64 + kdb;
            Af[lg + 0][kd] = (short)(u[j].x & 0xffff);
            Af[lg + 1][kd] = (short)(u[j].x >> 16);
            Af[lg + 2][kd] = (short)(u[j].y & 0xffff);
            Af[lg + 3][kd] = (short)(u[j].y >> 16);
        }
    }

    // ---- B tile staging: 512 o x 32 k per step; 4 x 16B per thread ----
    short8 nb0, nb1, nb2, nb3;
    const int ob = tid >> 2, jb = tid & 3;
    const int js = (jb ^ (ob & 3)) * 8;
    #define LOADB(k0) { \
        nb0 = *(const short8*)(Wbf + (size_t)(ob      ) * DM + (k0) + jb * 8); \
        nb1 = *(const short8*)(Wbf + (size_t)(ob + 128) * DM + (k0) + jb * 8); \
        nb2 = *(const short8*)(Wbf + (size_t)(ob + 256) * DM + (k0) + jb * 8); \
        nb3 = *(const short8*)(Wbf + (size_t)(ob + 384) * DM + (k0) + jb * 8); }
    #define WRITEB() { \
        *(short8*)&Bs[ob      ][js] = nb0; \
        *(short8*)&Bs[ob + 128][js] = nb1; \
        *(short8*)&Bs[ob + 256][js] = nb2; \
        *(short8*)&Bs[ob + 384][js] = nb3; }

    LOADB(0);
    WRITEB();
    LOADB(32);
    __syncthreads();

    f32x4 acc[2][4];
    #pragma unroll
    for (int a = 0; a < 2; ++a)
        #pragma unroll
        for (int nn = 0; nn < 4; ++nn)
            #pragma unroll
            for (int k = 0; k < 4; ++k) acc[a][nn][k] = 0.f;

    for (int k = 0; k < 16; ++k) {
        const int k0 = k * 32;
        short8 a0 = *(const short8*)&Af[m][k0 + q * 8];
        short8 a1 = *(const short8*)&Af[16 + m][k0 + q * 8];
        #pragma unroll
        for (int nf = 0; nf < 4; ++nf) {
            int o = w * 64 + nf * 16 + m;        // o&3 == m&3
            short8 bb = *(const short8*)&Bs[o][(q ^ (m & 3)) * 8];
            acc[0][nf] = __builtin_amdgcn_mfma_f32_16x16x32_bf16(a0, bb, acc[0][nf], 0, 0, 0);
            acc[1][nf] = __builtin_amdgcn_mfma_f32_16x16x32_bf16(a1, bb, acc[1][nf], 0, 0, 0);
        }
        __syncthreads();                          // all waves done reading Bs
        if (k < 15) {
            WRITEB();                             // B_{k+1} regs -> LDS
            if (k < 14) LOADB((k + 2) * 32);      // issue B_{k+2}; lands during next compute
            __syncthreads();                      // Bs ready
        }
    }
    #undef LOADB
    #undef WRITEB

    // ---- epilogue: +bias, +x residual, row mean/var, normalize ----
    float bo[4], ga[4], be[4];
    #pragma unroll
    for (int nf = 0; nf < 4; ++nf) {
        int o = w * 64 + nf * 16 + m;
        bo[nf] = bout[o]; ga[nf] = gamma[o]; be[nf] = beta[o];
    }

    float rs[2][4], rq[2][4];
    #pragma unroll
    for (int mf = 0; mf < 2; ++mf)
        #pragma unroll
        for (int i = 0; i < 4; ++i) { rs[mf][i] = 0.f; rq[mf][i] = 0.f; }

    #pragma unroll
    for (int mf = 0; mf < 2; ++mf)
        #pragma unroll
        for (int nf = 0; nf < 4; ++nf) {
            int o = w * 64 + nf * 16 + m;
            #pragma unroll
            for (int i = 0; i < 4; ++i) {
                int row = mf * 16 + q * 4 + i;    // C/D: row=(lane>>4)*4+reg, col=lane&15
                float zv = acc[mf][nf][i] + bo[nf] + x[(size_t)(r0 + row) * DM + o];
                acc[mf][nf][i] = zv;
                rs[mf][i] += zv;
                rq[mf][i] += zv * zv;
            }
        }

    #pragma unroll
    for (int mask = 1; mask < 16; mask <<= 1) {
        #pragma unroll
        for (int mf = 0; mf < 2; ++mf)
            #pragma unroll
            for (int i = 0; i < 4; ++i) {
                rs[mf][i] += __shfl_xor(rs[mf][i], mask);
                rq[mf][i] += __shfl_xor(rq[mf][i], mask);
            }
    }
    if (m == 0) {
        #pragma unroll
        for (int mf = 0; mf < 2; ++mf)
            #pragma unroll
            for (int i = 0; i < 4; ++i) {
                int row = mf * 16 + q * 4 + i;
                red[w][row][0] = rs[mf][i];
                red[w][row][1] = rq[mf][i];
            }
    }
    __syncthreads();
    if (tid < 32) {
        float s = 0.f, sq = 0.f;
        #pragma unroll
        for (int ww = 0; ww < 8; ++ww) { s += red[ww][tid][0]; sq += red[ww][tid][1]; }
        float mu  = s * (1.f / DM);
        float var = sq * (1.f / DM) - mu * mu;
        stats[tid][0] = mu;
        stats[tid][1] = 1.f / sqrtf(var + LN_EPS);
    }
    __syncthreads();

    #pragma unroll
    for (int mf = 0; mf < 2; ++mf)
        #pragma unroll
        for (int i = 0; i < 4; ++i) {
            int row = mf * 16 + q * 4 + i;
            float mu = stats[row][0], rstd = stats[row][1];
            #pragma unroll
            for (int nf = 0; nf < 4; ++nf) {
                int o = w * 64 + nf * 16 + m;
                out[(size_t)(r0 + row) * DM + o] =
                    ga[nf] * (acc[mf][nf][i] - mu) * rstd + be[nf];
            }
        }
}

// ---------------- launcher ----------------
// ATTRIBUTION ROUND: k_ssm launched 4x (idempotent). t_ssm = (T - 62.9)/3.
// gemm_ln reverted to v14 (round-20 measured-good). Revert ssm to 1x next round.
extern "C" void kernel_launch(void* const* d_in, const int* in_sizes, int n_in,
                              void* d_out, int out_size, void* d_ws, size_t ws_size,
                              hipStream_t stream)
{
    const float* x    = (const float*)d_in[0];
    const float* logA = (const float*)d_in[1];
    const float* Aim  = (const float*)d_in[2];
    const float* Bp   = (const float*)d_in[3];
    const float* Cp   = (const float*)d_in[4];
    const float* Dp   = (const float*)d_in[5];
    const float* W    = (const float*)d_in[6];
    const float* bo   = (const float*)d_in[7];
    const float* ga   = (const float*)d_in[8];
    const float* be   = (const float*)d_in[9];

    char* ws = (char*)d_ws;
    __hip_bfloat16* Wbf = (__hip_bfloat16*)ws;                   // 512 KiB @ 0
    __hip_bfloat16* xT  = (__hip_bfloat16*)(ws + (3u << 20));    // 8 MiB    @ 3M
    __hip_bfloat16* Mt  = (__hip_bfloat16*)(ws + (11u << 20));   // 12.6 MiB @ 11M
    __hip_bfloat16* yT  = (__hip_bfloat16*)(ws + (41u << 20));   // 8 MiB    @ 41M
    __hip_bfloat16* Gt  = (__hip_bfloat16*)(ws + (57u << 20));   // 8 MiB    @ 57M
    float2* e64         = (float2*)(ws + (65u << 20));           // 256 KiB  @ 65M

    k_prep   <<<3200, 256, 0, stream>>>(x, logA, Aim, Bp, Cp, W, xT, Wbf, Mt, Gt, e64);
    k_ssm    <<<DM, 256, 0, stream>>>(Gt, Mt, xT, e64, Dp, yT);
    k_ssm    <<<DM, 256, 0, stream>>>(Gt, Mt, xT, e64, Dp, yT);
    k_ssm    <<<DM, 256, 0, stream>>>(Gt, Mt, xT, e64, Dp, yT);
    k_ssm    <<<DM, 256, 0, stream>>>(Gt, Mt, xT, e64, Dp, yT);
    k_gemm_ln<<<(BATCH * SEQ) / 32, 512, 0, stream>>>(yT, Wbf, x, bo, ga, be, (float*)d_out);
}

// Round 25
// 52.571 us; speedup vs baseline: 1.9227x; 1.9227x over previous
//
#include <hip/hip_runtime.h>
#include <hip/hip_bf16.h>
#include <stdint.h>
#include <stddef.h>

#define BATCH 4
#define SEQ   2048
#define DM    512
#define NST   64
#define LN_EPS 1e-5f
#define NCH   32    // 32 chunks of 64
#define KDIM  192   // 64 x-taps + 128 carry (re,im interleaved)

typedef __attribute__((ext_vector_type(8))) short short8;
typedef __attribute__((ext_vector_type(4))) float f32x4;

__device__ __forceinline__ ushort f2bf(float f) {
    __hip_bfloat16 h = __float2bfloat16(f);
    return *(ushort*)&h;
}
__device__ __forceinline__ float bf2f(ushort u) {
    __hip_bfloat16 h = *(__hip_bfloat16*)&u;
    return __bfloat162float(h);
}

// ---------------- k_prep: x-transpose + W-convert (M/G build moved into k_ssm) ----------------
// blocks [0,2048):    x[b][l][d] f32 -> xT[d][b][l] bf16
// blocks [2048,3072): W->bf16
__global__ __launch_bounds__(256) void k_prep(
    const float* __restrict__ x, const float* __restrict__ W,
    __hip_bfloat16* __restrict__ xT, __hip_bfloat16* __restrict__ Wbf)
{
    __shared__ float smem[64][33];
    const int tid = threadIdx.x;
    const int bid = blockIdx.x;

    if (bid < 2048) {
        const int dt = bid & 15, lt = (bid >> 4) & 31, b = bid >> 9;
        const int l0 = lt * 64, d0 = dt * 32;
        const int dd = tid & 31, lr = tid >> 5;
        #pragma unroll
        for (int it = 0; it < 8; ++it) {
            int ll = it * 8 + lr;
            smem[ll][dd] = x[((size_t)b * SEQ + l0 + ll) * DM + d0 + dd];
        }
        __syncthreads();
        const int dw = tid >> 3, lg = (tid & 7) * 8;
        ushort pk[8];
        #pragma unroll
        for (int i = 0; i < 8; ++i) pk[i] = f2bf(smem[lg + i][dw]);
        *(short8*)&xT[((size_t)(d0 + dw) * BATCH + b) * SEQ + l0 + lg] = *(short8*)pk;
    } else {
        int i = (bid - 2048) * 256 + tid;
        if (i < DM * DM) Wbf[i] = __float2bfloat16(W[i]);
    }
}

// ---------------- k_ssm v2: in-block G/M build + scanU + carry + gemmY ----------------
// Per-d block. G_d, K, eA powers, M_d built IN LDS from raw params (no Mt/Gt buffers).
// Rgn union timeline (barrier-ordered): Gs(16K) -> Us(64.5K f32) -> Ms(24K).
// Phase 1: U = G*X (MFMA).  Phase 2: carry combine -> Zs carry chunks (bf16).
// Phase 3: y = M*Z (MFMA), +D*x, store yT[d][b][l].
__global__ __launch_bounds__(256) void k_ssm(
    const float* __restrict__ logA, const float* __restrict__ Aim,
    const float* __restrict__ Bp, const float* __restrict__ Cp,
    const __hip_bfloat16* __restrict__ xT, const float* __restrict__ Dp,
    __hip_bfloat16* __restrict__ yT)
{
    __shared__ short Zs[128 * 24 * 8];             // 48K: x chunks 0-7, carry chunks 8-23
    __shared__ __align__(16) char Rgn[128 * 129 * 4];   // 64.5K union: Gs / Us / Ms
    __shared__ float Klds[64];
    __shared__ float2 e64s[64];
    short* Gs = (short*)Rgn;
    float (*Us)[129] = (float(*)[129])Rgn;
    short* Ms = (short*)Rgn;

    const int tid = threadIdx.x;
    const int d = blockIdx.x;
    const int w = tid >> 6, lane = tid & 63;
    const int q = lane >> 4, n = lane & 15;

    // ---- issue Zs x-part loads early (land during G build) ----
    short8 xr[4];
    #pragma unroll
    for (int it = 0; it < 4; ++it) {
        int id = it * 256 + tid;
        int col = id >> 3, ck = id & 7;
        int bb = col >> 5, ch = col & 31;
        xr[it] = *(const short8*)&xT[((size_t)d * BATCH + bb) * SEQ + ch * 64 + ck * 8];
    }

    // ---- build G rows (2s,2s+1), K partials, carry entries; wave j covers t in [16j,16j+16) ----
    uint mca[16];                                  // packed (Re, -Im) of eA^(t+1) for M carry rows
    {
        const int s = lane;
        const int i = d * NST + s;
        float aa  = expf(logA[i]);
        float wim = Aim[i];
        float mag = expf(-aa);
        float er = mag * cosf(wim), ei = mag * sinf(wim);
        float Br = Bp[2*i], Bi = Bp[2*i+1];
        float Cr = Cp[2*i], Ci = Cp[2*i+1];
        float CBr = Cr*Br + Ci*Bi;
        float CBi = Cr*Bi - Ci*Br;

        // jump-start a = eA^(16w) via squarings (wave-uniform branches)
        float t2r = er*er - ei*ei,     t2i = 2.f*er*ei;
        float t4r = t2r*t2r - t2i*t2i, t4i = 2.f*t2r*t2i;
        float t8r = t4r*t4r - t4i*t4i, t8i = 2.f*t4r*t4i;
        float g16r = t8r*t8r - t8i*t8i, g16i = 2.f*t8r*t8i;   // eA^16
        float ar, ai;
        if (w == 0)      { ar = 1.f;  ai = 0.f; }
        else if (w == 1) { ar = g16r; ai = g16i; }
        else {
            float g32r = g16r*g16r - g16i*g16i, g32i = 2.f*g16r*g16i;
            if (w == 2)  { ar = g32r; ai = g32i; }
            else         { ar = g32r*g16r - g32i*g16i; ai = g32r*g16i + g32i*g16r; }
        }
        float prr = CBr*ar - CBi*ai;               // p = CB * eA^(16w)
        float pii = CBr*ai + CBi*ar;

        float kb[16];
        ushort gR[16], gI[16];
        #pragma unroll
        for (int tt = 0; tt < 16; ++tt) {
            kb[tt] = prr;
            gR[tt] = f2bf(prr);
            gI[tt] = f2bf(pii);
            float npr = er*prr - ei*pii, npi = er*pii + ei*prr;  prr = npr; pii = npi;
            float nar = er*ar - ei*ai,   nai = er*ai + ei*ar;    ar = nar; ai = nai;
            mca[tt] = (uint)f2bf(ar) | ((uint)f2bf(-ai) << 16);  // for M row 63-(16w+tt)
        }
        if (w == 3) e64s[s] = make_float2(ar, ai);               // eA^64

        // write Gs rows 2s (re) and 2s+1 (im), chunks 2w and 2w+1 (swizzled c^(row&7))
        short8 v;
        int row = 2 * s;
        #pragma unroll
        for (int e = 0; e < 8; ++e) v[e] = (short)gR[e];
        { int cs = (2*w) ^ (row & 7);     *(short8*)&Gs[(row * 8 + cs) * 8] = v; }
        #pragma unroll
        for (int e = 0; e < 8; ++e) v[e] = (short)gR[8 + e];
        { int cs = (2*w + 1) ^ (row & 7); *(short8*)&Gs[(row * 8 + cs) * 8] = v; }
        row = 2 * s + 1;
        #pragma unroll
        for (int e = 0; e < 8; ++e) v[e] = (short)gI[e];
        { int cs = (2*w) ^ (row & 7);     *(short8*)&Gs[(row * 8 + cs) * 8] = v; }
        #pragma unroll
        for (int e = 0; e < 8; ++e) v[e] = (short)gI[8 + e];
        { int cs = (2*w + 1) ^ (row & 7); *(short8*)&Gs[(row * 8 + cs) * 8] = v; }

        // K[t] = sum_s Re(CB*eA^t): 64-lane reduce per tt, lane 0 writes
        #pragma unroll
        for (int tt = 0; tt < 16; ++tt) {
            float v2 = kb[tt];
            #pragma unroll
            for (int mask = 1; mask < 64; mask <<= 1) v2 += __shfl_xor(v2, mask);
            if (lane == 0) Klds[16 * w + tt] = v2;
        }
    }

    // ---- write Zs x-part from prefetched regs ----
    #pragma unroll
    for (int it = 0; it < 4; ++it) {
        int id = it * 256 + tid;
        int col = id >> 3, ck = id & 7;
        int cs = ck ^ (col & 7);
        *(short8*)&Zs[(col * 24 + cs) * 8] = xr[it];
    }
    __syncthreads();                               // Gs, Zs-x, Klds, e64s ready

    // ---- phase 1: U = G * X ----
    f32x4 acc1[2][8];
    {
        #pragma unroll
        for (int rt = 0; rt < 2; ++rt)
            #pragma unroll
            for (int nf = 0; nf < 8; ++nf)
                #pragma unroll
                for (int k = 0; k < 4; ++k) acc1[rt][nf][k] = 0.f;

        #pragma unroll
        for (int rt = 0; rt < 2; ++rt) {
            const int arow = w * 32 + rt * 16 + n;
            #pragma unroll
            for (int kt = 0; kt < 2; ++kt) {
                int c = kt * 4 + q;
                int csa = c ^ (arow & 7);
                short8 af = *(const short8*)&Gs[(arow * 8 + csa) * 8];
                #pragma unroll
                for (int nf = 0; nf < 8; ++nf) {
                    int col = nf * 16 + n;
                    int csb = c ^ (col & 7);
                    short8 bf = *(const short8*)&Zs[(col * 24 + csb) * 8];
                    acc1[rt][nf] = __builtin_amdgcn_mfma_f32_16x16x32_bf16(af, bf, acc1[rt][nf], 0, 0, 0);
                }
            }
        }
    }
    __syncthreads();                               // Gs reads done; Rgn becomes Us

    #pragma unroll
    for (int rt = 0; rt < 2; ++rt) {
        const int r0w = w * 32 + rt * 16 + q * 4;
        #pragma unroll
        for (int nf = 0; nf < 8; ++nf) {
            int col = nf * 16 + n;
            #pragma unroll
            for (int r = 0; r < 4; ++r) Us[r0w + r][col] = acc1[rt][nf][r];
        }
    }
    __syncthreads();                               // Us ready

    // ---- phase 2: carry combine, bf16 straight into Zs carry chunks ----
    {
        const int bb = tid >> 6, s = tid & 63;
        const int st = s >> 2, so = (s & 3) * 2;
        float2 a64 = e64s[s];
        const float er = a64.x, ei = a64.y;
        {
            int col = bb * 32 + 31;
            int c = 8 + st, cs = (c & ~7) | ((c & 7) ^ (col & 7));
            *(uint*)&Zs[(col * 24 + cs) * 8 + so] = 0u;
        }
        float gr = Us[2 * s][bb * 32 + 31], gi = Us[2 * s + 1][bb * 32 + 31];
        {
            int col = bb * 32 + 30;
            int c = 8 + st, cs = (c & ~7) | ((c & 7) ^ (col & 7));
            *(uint*)&Zs[(col * 24 + cs) * 8 + so] = (uint)f2bf(gr) | ((uint)f2bf(gi) << 16);
        }
        for (int ch = 30; ch >= 1; --ch) {
            float ur = Us[2 * s][bb * 32 + ch], ui = Us[2 * s + 1][bb * 32 + ch];
            float nr = ur + er * gr - ei * gi;
            float ni = ui + er * gi + ei * gr;
            gr = nr; gi = ni;
            int col = bb * 32 + ch - 1;
            int c = 8 + st, cs = (c & ~7) | ((c & 7) ^ (col & 7));
            *(uint*)&Zs[(col * 24 + cs) * 8 + so] = (uint)f2bf(gr) | ((uint)f2bf(gi) << 16);
        }
    }
    __syncthreads();                               // Us reads done; Rgn becomes Ms

    // ---- build Ms: K-part (chunks 0-7) from Klds, carry-part (chunks 8-23) from mca regs ----
    {
        #pragma unroll
        for (int it = 0; it < 2; ++it) {
            int id = it * 256 + tid;               // 0..511
            int row = id >> 3, c = id & 7;
            short8 v;
            #pragma unroll
            for (int e = 0; e < 8; ++e) {
                int col = c * 8 + e;
                float kv = (col >= row) ? Klds[col - row] : 0.f;
                v[e] = (short)f2bf(kv);
            }
            int cs = c ^ (row & 7);
            *(short8*)&Ms[(row * 24 + cs) * 8] = v;
        }
        const int s = lane;
        const int cc = 8 + (s >> 2);
        const int soff = 2 * (s & 3);
        #pragma unroll
        for (int tt = 0; tt < 16; ++tt) {
            int row = 63 - (16 * w + tt);
            int cs = (cc & ~7) | ((cc & 7) ^ (row & 7));
            *(uint*)&Ms[(row * 24 + cs) * 8 + soff] = mca[tt];
        }
    }
    __syncthreads();                               // Ms ready

    // ---- phase 3: y = M * Z, + D*x, store yT ----
    f32x4 acc[8];
    #pragma unroll
    for (int nf = 0; nf < 8; ++nf)
        #pragma unroll
        for (int k = 0; k < 4; ++k) acc[nf][k] = 0.f;

    const int arow = w * 16 + n;
    #pragma unroll
    for (int kt = 0; kt < 6; ++kt) {
        int c = kt * 4 + q;
        int csa = (c & ~7) | ((c & 7) ^ (arow & 7));
        short8 af = *(const short8*)&Ms[(arow * 24 + csa) * 8];
        #pragma unroll
        for (int nf = 0; nf < 8; ++nf) {
            int col = nf * 16 + n;
            int csb = (c & ~7) | ((c & 7) ^ (col & 7));
            short8 bfr = *(const short8*)&Zs[(col * 24 + csb) * 8];
            acc[nf] = __builtin_amdgcn_mfma_f32_16x16x32_bf16(af, bfr, acc[nf], 0, 0, 0);
        }
    }

    const float Dd = Dp[d];
    const int i0 = w * 16 + q * 4;
    #pragma unroll
    for (int nf = 0; nf < 8; ++nf) {
        int col = nf * 16 + n;
        int bb = col >> 5, ch = col & 31;
        int cx = (i0 >> 3) ^ (col & 7);
        const ushort* zp = (const ushort*)&Zs[(col * 24 + cx) * 8 + (i0 & 7)];
        ushort o[4];
        #pragma unroll
        for (int r = 0; r < 4; ++r)
            o[r] = f2bf(acc[nf][r] + Dd * bf2f(zp[r]));
        *(uint2*)&yT[((size_t)d * BATCH + bb) * SEQ + ch * 64 + i0] = *(uint2*)o;
    }
}

// ---------------- k_gemm_ln v14: A panel direct from yT + dbuf reg-staged B (round-20 proven) ----------------
__global__ __launch_bounds__(512) void k_gemm_ln(
    const __hip_bfloat16* __restrict__ yT, const __hip_bfloat16* __restrict__ Wbf,
    const float* __restrict__ x, const float* __restrict__ bout,
    const float* __restrict__ gamma, const float* __restrict__ beta,
    float* __restrict__ out)
{
    __shared__ short Af[32][520];     // full A panel [l][kd]; stride 520
    __shared__ short Bs[512][32];     // W tile [o][k], 16B-chunk XOR swizzle (validated)
    __shared__ float red[8][32][2];
    __shared__ float stats[32][2];

    const int tid  = threadIdx.x;
    const int w    = tid >> 6;
    const int lane = tid & 63;
    const int q    = lane >> 4;
    const int m    = lane & 15;
    const int r0   = blockIdx.x * 32;
    const int bq   = r0 >> 11;           // batch index (r0 32-aligned, no straddle)
    const int l0   = r0 & 2047;

    // ---- one-time A panel from yT[d][b][l]: thread (kdb, lg) reads 8 overlapped uint2 ----
    {
        const int kdb = tid >> 3, lg = (tid & 7) * 4;
        uint2 u[8];
        #pragma unroll
        for (int j = 0; j < 8; ++j)
            u[j] = *(const uint2*)&yT[((size_t)(j * 64 + kdb) * BATCH + bq) * SEQ + l0 + lg];
        #pragma unroll
        for (int j = 0; j < 8; ++j) {
            int kd = j * 64 + kdb;
            Af[lg + 0][kd] = (short)(u[j].x & 0xffff);
            Af[lg + 1][kd] = (short)(u[j].x >> 16);
            Af[lg + 2][kd] = (short)(u[j].y & 0xffff);
            Af[lg + 3][kd] = (short)(u[j].y >> 16);
        }
    }

    // ---- B tile staging: 512 o x 32 k per step; 4 x 16B per thread ----
    short8 nb0, nb1, nb2, nb3;
    const int ob = tid >> 2, jb = tid & 3;
    const int js = (jb ^ (ob & 3)) * 8;
    #define LOADB(k0) { \
        nb0 = *(const short8*)(Wbf + (size_t)(ob      ) * DM + (k0) + jb * 8); \
        nb1 = *(const short8*)(Wbf + (size_t)(ob + 128) * DM + (k0) + jb * 8); \
        nb2 = *(const short8*)(Wbf + (size_t)(ob + 256) * DM + (k0) + jb * 8); \
        nb3 = *(const short8*)(Wbf + (size_t)(ob + 384) * DM + (k0) + jb * 8); }
    #define WRITEB() { \
        *(short8*)&Bs[ob      ][js] = nb0; \
        *(short8*)&Bs[ob + 128][js] = nb1; \
        *(short8*)&Bs[ob + 256][js] = nb2; \
        *(short8*)&Bs[ob + 384][js] = nb3; }

    LOADB(0);
    WRITEB();
    LOADB(32);
    __syncthreads();

    f32x4 acc[2][4];
    #pragma unroll
    for (int a = 0; a < 2; ++a)
        #pragma unroll
        for (int nn = 0; nn < 4; ++nn)
            #pragma unroll
            for (int k = 0; k < 4; ++k) acc[a][nn][k] = 0.f;

    for (int k = 0; k < 16; ++k) {
        const int k0 = k * 32;
        short8 a0 = *(const short8*)&Af[m][k0 + q * 8];
        short8 a1 = *(const short8*)&Af[16 + m][k0 + q * 8];
        #pragma unroll
        for (int nf = 0; nf < 4; ++nf) {
            int o = w * 64 + nf * 16 + m;        // o&3 == m&3
            short8 bb = *(const short8*)&Bs[o][(q ^ (m & 3)) * 8];
            acc[0][nf] = __builtin_amdgcn_mfma_f32_16x16x32_bf16(a0, bb, acc[0][nf], 0, 0, 0);
            acc[1][nf] = __builtin_amdgcn_mfma_f32_16x16x32_bf16(a1, bb, acc[1][nf], 0, 0, 0);
        }
        __syncthreads();                          // all waves done reading Bs
        if (k < 15) {
            WRITEB();                             // B_{k+1} regs -> LDS
            if (k < 14) LOADB((k + 2) * 32);      // issue B_{k+2}; lands during next compute
            __syncthreads();                      // Bs ready
        }
    }
    #undef LOADB
    #undef WRITEB

    // ---- epilogue: +bias, +x residual, row mean/var, normalize ----
    float bo[4], ga[4], be[4];
    #pragma unroll
    for (int nf = 0; nf < 4; ++nf) {
        int o = w * 64 + nf * 16 + m;
        bo[nf] = bout[o]; ga[nf] = gamma[o]; be[nf] = beta[o];
    }

    float rs[2][4], rq[2][4];
    #pragma unroll
    for (int mf = 0; mf < 2; ++mf)
        #pragma unroll
        for (int i = 0; i < 4; ++i) { rs[mf][i] = 0.f; rq[mf][i] = 0.f; }

    #pragma unroll
    for (int mf = 0; mf < 2; ++mf)
        #pragma unroll
        for (int nf = 0; nf < 4; ++nf) {
            int o = w * 64 + nf * 16 + m;
            #pragma unroll
            for (int i = 0; i < 4; ++i) {
                int row = mf * 16 + q * 4 + i;    // C/D: row=(lane>>4)*4+reg, col=lane&15
                float zv = acc[mf][nf][i] + bo[nf] + x[(size_t)(r0 + row) * DM + o];
                acc[mf][nf][i] = zv;
                rs[mf][i] += zv;
                rq[mf][i] += zv * zv;
            }
        }

    #pragma unroll
    for (int mask = 1; mask < 16; mask <<= 1) {
        #pragma unroll
        for (int mf = 0; mf < 2; ++mf)
            #pragma unroll
            for (int i = 0; i < 4; ++i) {
                rs[mf][i] += __shfl_xor(rs[mf][i], mask);
                rq[mf][i] += __shfl_xor(rq[mf][i], mask);
            }
    }
    if (m == 0) {
        #pragma unroll
        for (int mf = 0; mf < 2; ++mf)
            #pragma unroll
            for (int i = 0; i < 4; ++i) {
                int row = mf * 16 + q * 4 + i;
                red[w][row][0] = rs[mf][i];
                red[w][row][1] = rq[mf][i];
            }
    }
    __syncthreads();
    if (tid < 32) {
        float s = 0.f, sq = 0.f;
        #pragma unroll
        for (int ww = 0; ww < 8; ++ww) { s += red[ww][tid][0]; sq += red[ww][tid][1]; }
        float mu  = s * (1.f / DM);
        float var = sq * (1.f / DM) - mu * mu;
        stats[tid][0] = mu;
        stats[tid][1] = 1.f / sqrtf(var + LN_EPS);
    }
    __syncthreads();

    #pragma unroll
    for (int mf = 0; mf < 2; ++mf)
        #pragma unroll
        for (int i = 0; i < 4; ++i) {
            int row = mf * 16 + q * 4 + i;
            float mu = stats[row][0], rstd = stats[row][1];
            #pragma unroll
            for (int nf = 0; nf < 4; ++nf) {
                int o = w * 64 + nf * 16 + m;
                out[(size_t)(r0 + row) * DM + o] =
                    ga[nf] * (acc[mf][nf][i] - mu) * rstd + be[nf];
            }
        }
}

// ---------------- launcher ----------------
extern "C" void kernel_launch(void* const* d_in, const int* in_sizes, int n_in,
                              void* d_out, int out_size, void* d_ws, size_t ws_size,
                              hipStream_t stream)
{
    const float* x    = (const float*)d_in[0];
    const float* logA = (const float*)d_in[1];
    const float* Aim  = (const float*)d_in[2];
    const float* Bp   = (const float*)d_in[3];
    const float* Cp   = (const float*)d_in[4];
    const float* Dp   = (const float*)d_in[5];
    const float* W    = (const float*)d_in[6];
    const float* bo   = (const float*)d_in[7];
    const float* ga   = (const float*)d_in[8];
    const float* be   = (const float*)d_in[9];

    char* ws = (char*)d_ws;
    __hip_bfloat16* Wbf = (__hip_bfloat16*)ws;                   // 512 KiB @ 0
    __hip_bfloat16* xT  = (__hip_bfloat16*)(ws + (3u << 20));    // 8 MiB    @ 3M
    __hip_bfloat16* yT  = (__hip_bfloat16*)(ws + (41u << 20));   // 8 MiB    @ 41M

    k_prep   <<<3072, 256, 0, stream>>>(x, W, xT, Wbf);
    k_ssm    <<<DM, 256, 0, stream>>>(logA, Aim, Bp, Cp, xT, Dp, yT);
    k_gemm_ln<<<(BATCH * SEQ) / 32, 512, 0, stream>>>(yT, Wbf, x, bo, ga, be, (float*)d_out);
}

// Round 26
// 48.504 us; speedup vs baseline: 2.0839x; 1.0838x over previous
//
#include <hip/hip_runtime.h>
#include <hip/hip_bf16.h>
#include <stdint.h>
#include <stddef.h>

#define BATCH 4
#define SEQ   2048
#define DM    512
#define NST   64
#define LN_EPS 1e-5f
#define NCH   32
#define KDIM  192

typedef __attribute__((ext_vector_type(8))) short short8;
typedef __attribute__((ext_vector_type(4))) float f32x4;

__device__ __forceinline__ ushort f2bf(float f) {
    __hip_bfloat16 h = __float2bfloat16(f);
    return *(ushort*)&h;
}
__device__ __forceinline__ float bf2f(ushort u) {
    __hip_bfloat16 h = *(__hip_bfloat16*)&u;
    return __bfloat162float(h);
}

// ---------------- k_prep: x-transpose + W-convert ----------------
__global__ __launch_bounds__(256) void k_prep(
    const float* __restrict__ x, const float* __restrict__ W,
    __hip_bfloat16* __restrict__ xT, __hip_bfloat16* __restrict__ Wbf)
{
    __shared__ float smem[64][33];
    const int tid = threadIdx.x;
    const int bid = blockIdx.x;

    if (bid < 2048) {
        const int dt = bid & 15, lt = (bid >> 4) & 31, b = bid >> 9;
        const int l0 = lt * 64, d0 = dt * 32;
        const int dd = tid & 31, lr = tid >> 5;
        #pragma unroll
        for (int it = 0; it < 8; ++it) {
            int ll = it * 8 + lr;
            smem[ll][dd] = x[((size_t)b * SEQ + l0 + ll) * DM + d0 + dd];
        }
        __syncthreads();
        const int dw = tid >> 3, lg = (tid & 7) * 8;
        ushort pk[8];
        #pragma unroll
        for (int i = 0; i < 8; ++i) pk[i] = f2bf(smem[lg + i][dw]);
        *(short8*)&xT[((size_t)(d0 + dw) * BATCH + b) * SEQ + l0 + lg] = *(short8*)pk;
    } else {
        int i = (bid - 2048) * 256 + tid;
        if (i < DM * DM) Wbf[i] = __float2bfloat16(W[i]);
    }
}

// ---------------- k_ssm v3: 512 threads (2 waves/SIMD), in-block G/M build + 3 MFMA phases ----------------
// Round-25 PMC: v2 at 256 thr was 1 wave/SIMD, all pipes <10% busy (pure exposed latency).
// v3: 8 waves; G-build wave j covers t in [8j,8j+8); phase1 = 1 row-tile/wave;
// phase3 = (row-tile, col-half)/wave. Layouts/swizzles identical to v2.
__global__ __launch_bounds__(512) void k_ssm(
    const float* __restrict__ logA, const float* __restrict__ Aim,
    const float* __restrict__ Bp, const float* __restrict__ Cp,
    const __hip_bfloat16* __restrict__ xT, const float* __restrict__ Dp,
    __hip_bfloat16* __restrict__ yT)
{
    __shared__ short Zs[128 * 24 * 8];             // 48K: x chunks 0-7, carry chunks 8-23
    __shared__ __align__(16) char Rgn[128 * 129 * 4];   // 64.5K union: Gs / Us / Ms
    __shared__ float Klds[64];
    __shared__ float2 e64s[64];
    short* Gs = (short*)Rgn;
    float (*Us)[129] = (float(*)[129])Rgn;
    short* Ms = (short*)Rgn;

    const int tid = threadIdx.x;
    const int d = blockIdx.x;
    const int w = tid >> 6, lane = tid & 63;
    const int q = lane >> 4, n = lane & 15;

    // ---- issue Zs x-part loads early (land during G build) ----
    short8 xr[2];
    #pragma unroll
    for (int it = 0; it < 2; ++it) {
        int id = it * 512 + tid;
        int col = id >> 3, ck = id & 7;
        int bb = col >> 5, ch = col & 31;
        xr[it] = *(const short8*)&xT[((size_t)d * BATCH + bb) * SEQ + ch * 64 + ck * 8];
    }

    // ---- build G rows (2s,2s+1) chunk w, K partials, carry entries; wave j covers t in [8j,8j+8) ----
    uint mca[8];                                   // packed (Re, -Im) of eA^(t+1) for M carry rows
    {
        const int s = lane;
        const int i = d * NST + s;
        float aa  = expf(logA[i]);
        float wim = Aim[i];
        float mag = expf(-aa);
        float er = mag * cosf(wim), ei = mag * sinf(wim);
        float Br = Bp[2*i], Bi = Bp[2*i+1];
        float Cr = Cp[2*i], Ci = Cp[2*i+1];
        float CBr = Cr*Br + Ci*Bi;
        float CBi = Cr*Bi - Ci*Br;

        // jump-start a = eA^(8w) via squarings/products (wave-uniform branches)
        float e2r = er*er - ei*ei,   e2i = 2.f*er*ei;
        float e4r = e2r*e2r - e2i*e2i, e4i = 2.f*e2r*e2i;
        float e8r = e4r*e4r - e4i*e4i, e8i = 2.f*e4r*e4i;       // eA^8
        float ar, ai;
        if (w == 0)      { ar = 1.f;  ai = 0.f; }
        else if (w == 1) { ar = e8r;  ai = e8i; }
        else {
            float e16r = e8r*e8r - e8i*e8i, e16i = 2.f*e8r*e8i;
            if (w == 2)      { ar = e16r; ai = e16i; }
            else if (w == 3) { ar = e16r*e8r - e16i*e8i;  ai = e16r*e8i + e16i*e8r; }
            else {
                float e32r = e16r*e16r - e16i*e16i, e32i = 2.f*e16r*e16i;
                if (w == 4)      { ar = e32r; ai = e32i; }
                else if (w == 5) { ar = e32r*e8r - e32i*e8i;   ai = e32r*e8i + e32i*e8r; }
                else if (w == 6) { ar = e32r*e16r - e32i*e16i; ai = e32r*e16i + e32i*e16r; }
                else {
                    float e48r = e32r*e16r - e32i*e16i, e48i = e32r*e16i + e32i*e16r;
                    ar = e48r*e8r - e48i*e8i;  ai = e48r*e8i + e48i*e8r;   // eA^56
                }
            }
        }
        float prr = CBr*ar - CBi*ai;               // p = CB * eA^(8w)
        float pii = CBr*ai + CBi*ar;

        float kb[8];
        ushort gR[8], gI[8];
        #pragma unroll
        for (int tt = 0; tt < 8; ++tt) {
            kb[tt] = prr;
            gR[tt] = f2bf(prr);
            gI[tt] = f2bf(pii);
            float npr = er*prr - ei*pii, npi = er*pii + ei*prr;  prr = npr; pii = npi;
            float nar = er*ar - ei*ai,   nai = er*ai + ei*ar;    ar = nar; ai = nai;
            mca[tt] = (uint)f2bf(ar) | ((uint)f2bf(-ai) << 16);  // for M row 63-(8w+tt)
        }
        if (w == 7) e64s[s] = make_float2(ar, ai);               // eA^64

        short8 v;
        int row = 2 * s;
        #pragma unroll
        for (int e = 0; e < 8; ++e) v[e] = (short)gR[e];
        { int cs = w ^ (row & 7); *(short8*)&Gs[(row * 8 + cs) * 8] = v; }
        row = 2 * s + 1;
        #pragma unroll
        for (int e = 0; e < 8; ++e) v[e] = (short)gI[e];
        { int cs = w ^ (row & 7); *(short8*)&Gs[(row * 8 + cs) * 8] = v; }

        #pragma unroll
        for (int tt = 0; tt < 8; ++tt) {
            float v2 = kb[tt];
            #pragma unroll
            for (int mask = 1; mask < 64; mask <<= 1) v2 += __shfl_xor(v2, mask);
            if (lane == 0) Klds[8 * w + tt] = v2;
        }
    }

    // ---- write Zs x-part from prefetched regs ----
    #pragma unroll
    for (int it = 0; it < 2; ++it) {
        int id = it * 512 + tid;
        int col = id >> 3, ck = id & 7;
        int cs = ck ^ (col & 7);
        *(short8*)&Zs[(col * 24 + cs) * 8] = xr[it];
    }
    __syncthreads();                               // Gs, Zs-x, Klds, e64s ready

    // ---- phase 1: U = G * X (wave w owns row-tile w: rows 16w..16w+15) ----
    f32x4 acc1[8];
    {
        #pragma unroll
        for (int nf = 0; nf < 8; ++nf)
            #pragma unroll
            for (int k = 0; k < 4; ++k) acc1[nf][k] = 0.f;

        const int arow = w * 16 + n;
        #pragma unroll
        for (int kt = 0; kt < 2; ++kt) {
            int c = kt * 4 + q;
            int csa = c ^ (arow & 7);
            short8 af = *(const short8*)&Gs[(arow * 8 + csa) * 8];
            #pragma unroll
            for (int nf = 0; nf < 8; ++nf) {
                int col = nf * 16 + n;
                int csb = c ^ (col & 7);
                short8 bf = *(const short8*)&Zs[(col * 24 + csb) * 8];
                acc1[nf] = __builtin_amdgcn_mfma_f32_16x16x32_bf16(af, bf, acc1[nf], 0, 0, 0);
            }
        }
    }
    __syncthreads();                               // Gs reads done; Rgn becomes Us

    {
        const int r0w = w * 16 + q * 4;
        #pragma unroll
        for (int nf = 0; nf < 8; ++nf) {
            int col = nf * 16 + n;
            #pragma unroll
            for (int r = 0; r < 4; ++r) Us[r0w + r][col] = acc1[nf][r];
        }
    }
    __syncthreads();                               // Us ready

    // ---- phase 2: carry combine (tid<256), bf16 straight into Zs carry chunks ----
    if (tid < 256) {
        const int bb = tid >> 6, s = tid & 63;
        const int st = s >> 2, so = (s & 3) * 2;
        float2 a64 = e64s[s];
        const float er = a64.x, ei = a64.y;
        {
            int col = bb * 32 + 31;
            int c = 8 + st, cs = (c & ~7) | ((c & 7) ^ (col & 7));
            *(uint*)&Zs[(col * 24 + cs) * 8 + so] = 0u;
        }
        float gr = Us[2 * s][bb * 32 + 31], gi = Us[2 * s + 1][bb * 32 + 31];
        {
            int col = bb * 32 + 30;
            int c = 8 + st, cs = (c & ~7) | ((c & 7) ^ (col & 7));
            *(uint*)&Zs[(col * 24 + cs) * 8 + so] = (uint)f2bf(gr) | ((uint)f2bf(gi) << 16);
        }
        #pragma unroll 6
        for (int ch = 30; ch >= 1; --ch) {
            float ur = Us[2 * s][bb * 32 + ch], ui = Us[2 * s + 1][bb * 32 + ch];
            float nr = ur + er * gr - ei * gi;
            float ni = ui + er * gi + ei * gr;
            gr = nr; gi = ni;
            int col = bb * 32 + ch - 1;
            int c = 8 + st, cs = (c & ~7) | ((c & 7) ^ (col & 7));
            *(uint*)&Zs[(col * 24 + cs) * 8 + so] = (uint)f2bf(gr) | ((uint)f2bf(gi) << 16);
        }
    }
    __syncthreads();                               // Us reads done; Rgn becomes Ms

    // ---- build Ms: K-part (chunks 0-7) from Klds, carry-part (chunks 8-23) from mca regs ----
    {
        {
            int id = tid;                          // 0..511 = 64 rows x 8 chunks
            int row = id >> 3, c = id & 7;
            short8 v;
            #pragma unroll
            for (int e = 0; e < 8; ++e) {
                int col = c * 8 + e;
                float kv = (col >= row) ? Klds[col - row] : 0.f;
                v[e] = (short)f2bf(kv);
            }
            int cs = c ^ (row & 7);
            *(short8*)&Ms[(row * 24 + cs) * 8] = v;
        }
        const int s = lane;
        const int cc = 8 + (s >> 2);
        const int soff = 2 * (s & 3);
        #pragma unroll
        for (int tt = 0; tt < 8; ++tt) {
            int row = 63 - (8 * w + tt);
            int cs = (cc & ~7) | ((cc & 7) ^ (row & 7));
            *(uint*)&Ms[(row * 24 + cs) * 8 + soff] = mca[tt];
        }
    }
    __syncthreads();                               // Ms ready

    // ---- phase 3: y = M * Z; wave w -> row-tile w>>1, col-half w&1 ----
    f32x4 acc[4];
    #pragma unroll
    for (int nf = 0; nf < 4; ++nf)
        #pragma unroll
        for (int k = 0; k < 4; ++k) acc[nf][k] = 0.f;

    const int arow = (w >> 1) * 16 + n;
    const int nfb  = (w & 1) * 4;
    #pragma unroll
    for (int kt = 0; kt < 6; ++kt) {
        int c = kt * 4 + q;
        int csa = (c & ~7) | ((c & 7) ^ (arow & 7));
        short8 af = *(const short8*)&Ms[(arow * 24 + csa) * 8];
        #pragma unroll
        for (int j = 0; j < 4; ++j) {
            int col = (nfb + j) * 16 + n;
            int csb = (c & ~7) | ((c & 7) ^ (col & 7));
            short8 bfr = *(const short8*)&Zs[(col * 24 + csb) * 8];
            acc[j] = __builtin_amdgcn_mfma_f32_16x16x32_bf16(af, bfr, acc[j], 0, 0, 0);
        }
    }

    const float Dd = Dp[d];
    const int i0 = (w >> 1) * 16 + q * 4;
    #pragma unroll
    for (int j = 0; j < 4; ++j) {
        int col = (nfb + j) * 16 + n;
        int bb = col >> 5, ch = col & 31;
        int cx = (i0 >> 3) ^ (col & 7);
        const ushort* zp = (const ushort*)&Zs[(col * 24 + cx) * 8 + (i0 & 7)];
        ushort o[4];
        #pragma unroll
        for (int r = 0; r < 4; ++r)
            o[r] = f2bf(acc[j][r] + Dd * bf2f(zp[r]));
        *(uint2*)&yT[((size_t)d * BATCH + bb) * SEQ + ch * 64 + i0] = *(uint2*)o;
    }
}

// ---------------- k_gemm_ln v14: A panel direct from yT + dbuf reg-staged B (round-20 proven) ----------------
__global__ __launch_bounds__(512) void k_gemm_ln(
    const __hip_bfloat16* __restrict__ yT, const __hip_bfloat16* __restrict__ Wbf,
    const float* __restrict__ x, const float* __restrict__ bout,
    const float* __restrict__ gamma, const float* __restrict__ beta,
    float* __restrict__ out)
{
    __shared__ short Af[32][520];
    __shared__ short Bs[512][32];
    __shared__ float red[8][32][2];
    __shared__ float stats[32][2];

    const int tid  = threadIdx.x;
    const int w    = tid >> 6;
    const int lane = tid & 63;
    const int q    = lane >> 4;
    const int m    = lane & 15;
    const int r0   = blockIdx.x * 32;
    const int bq   = r0 >> 11;
    const int l0   = r0 & 2047;

    {
        const int kdb = tid >> 3, lg = (tid & 7) * 4;
        uint2 u[8];
        #pragma unroll
        for (int j = 0; j < 8; ++j)
            u[j] = *(const uint2*)&yT[((size_t)(j * 64 + kdb) * BATCH + bq) * SEQ + l0 + lg];
        #pragma unroll
        for (int j = 0; j < 8; ++j) {
            int kd = j * 64 + kdb;
            Af[lg + 0][kd] = (short)(u[j].x & 0xffff);
            Af[lg + 1][kd] = (short)(u[j].x >> 16);
            Af[lg + 2][kd] = (short)(u[j].y & 0xffff);
            Af[lg + 3][kd] = (short)(u[j].y >> 16);
        }
    }

    short8 nb0, nb1, nb2, nb3;
    const int ob = tid >> 2, jb = tid & 3;
    const int js = (jb ^ (ob & 3)) * 8;
    #define LOADB(k0) { \
        nb0 = *(const short8*)(Wbf + (size_t)(ob      ) * DM + (k0) + jb * 8); \
        nb1 = *(const short8*)(Wbf + (size_t)(ob + 128) * DM + (k0) + jb * 8); \
        nb2 = *(const short8*)(Wbf + (size_t)(ob + 256) * DM + (k0) + jb * 8); \
        nb3 = *(const short8*)(Wbf + (size_t)(ob + 384) * DM + (k0) + jb * 8); }
    #define WRITEB() { \
        *(short8*)&Bs[ob      ][js] = nb0; \
        *(short8*)&Bs[ob + 128][js] = nb1; \
        *(short8*)&Bs[ob + 256][js] = nb2; \
        *(short8*)&Bs[ob + 384][js] = nb3; }

    LOADB(0);
    WRITEB();
    LOADB(32);
    __syncthreads();

    f32x4 acc[2][4];
    #pragma unroll
    for (int a = 0; a < 2; ++a)
        #pragma unroll
        for (int nn = 0; nn < 4; ++nn)
            #pragma unroll
            for (int k = 0; k < 4; ++k) acc[a][nn][k] = 0.f;

    for (int k = 0; k < 16; ++k) {
        const int k0 = k * 32;
        short8 a0 = *(const short8*)&Af[m][k0 + q * 8];
        short8 a1 = *(const short8*)&Af[16 + m][k0 + q * 8];
        #pragma unroll
        for (int nf = 0; nf < 4; ++nf) {
            int o = w * 64 + nf * 16 + m;
            short8 bb = *(const short8*)&Bs[o][(q ^ (m & 3)) * 8];
            acc[0][nf] = __builtin_amdgcn_mfma_f32_16x16x32_bf16(a0, bb, acc[0][nf], 0, 0, 0);
            acc[1][nf] = __builtin_amdgcn_mfma_f32_16x16x32_bf16(a1, bb, acc[1][nf], 0, 0, 0);
        }
        __syncthreads();
        if (k < 15) {
            WRITEB();
            if (k < 14) LOADB((k + 2) * 32);
            __syncthreads();
        }
    }
    #undef LOADB
    #undef WRITEB

    float bo[4], ga[4], be[4];
    #pragma unroll
    for (int nf = 0; nf < 4; ++nf) {
        int o = w * 64 + nf * 16 + m;
        bo[nf] = bout[o]; ga[nf] = gamma[o]; be[nf] = beta[o];
    }

    float rs[2][4], rq[2][4];
    #pragma unroll
    for (int mf = 0; mf < 2; ++mf)
        #pragma unroll
        for (int i = 0; i < 4; ++i) { rs[mf][i] = 0.f; rq[mf][i] = 0.f; }

    #pragma unroll
    for (int mf = 0; mf < 2; ++mf)
        #pragma unroll
        for (int nf = 0; nf < 4; ++nf) {
            int o = w * 64 + nf * 16 + m;
            #pragma unroll
            for (int i = 0; i < 4; ++i) {
                int row = mf * 16 + q * 4 + i;
                float zv = acc[mf][nf][i] + bo[nf] + x[(size_t)(r0 + row) * DM + o];
                acc[mf][nf][i] = zv;
                rs[mf][i] += zv;
                rq[mf][i] += zv * zv;
            }
        }

    #pragma unroll
    for (int mask = 1; mask < 16; mask <<= 1) {
        #pragma unroll
        for (int mf = 0; mf < 2; ++mf)
            #pragma unroll
            for (int i = 0; i < 4; ++i) {
                rs[mf][i] += __shfl_xor(rs[mf][i], mask);
                rq[mf][i] += __shfl_xor(rq[mf][i], mask);
            }
    }
    if (m == 0) {
        #pragma unroll
        for (int mf = 0; mf < 2; ++mf)
            #pragma unroll
            for (int i = 0; i < 4; ++i) {
                int row = mf * 16 + q * 4 + i;
                red[w][row][0] = rs[mf][i];
                red[w][row][1] = rq[mf][i];
            }
    }
    __syncthreads();
    if (tid < 32) {
        float s = 0.f, sq = 0.f;
        #pragma unroll
        for (int ww = 0; ww < 8; ++ww) { s += red[ww][tid][0]; sq += red[ww][tid][1]; }
        float mu  = s * (1.f / DM);
        float var = sq * (1.f / DM) - mu * mu;
        stats[tid][0] = mu;
        stats[tid][1] = 1.f / sqrtf(var + LN_EPS);
    }
    __syncthreads();

    #pragma unroll
    for (int mf = 0; mf < 2; ++mf)
        #pragma unroll
        for (int i = 0; i < 4; ++i) {
            int row = mf * 16 + q * 4 + i;
            float mu = stats[row][0], rstd = stats[row][1];
            #pragma unroll
            for (int nf = 0; nf < 4; ++nf) {
                int o = w * 64 + nf * 16 + m;
                out[(size_t)(r0 + row) * DM + o] =
                    ga[nf] * (acc[mf][nf][i] - mu) * rstd + be[nf];
            }
        }
}

// ---------------- launcher ----------------
extern "C" void kernel_launch(void* const* d_in, const int* in_sizes, int n_in,
                              void* d_out, int out_size, void* d_ws, size_t ws_size,
                              hipStream_t stream)
{
    const float* x    = (const float*)d_in[0];
    const float* logA = (const float*)d_in[1];
    const float* Aim  = (const float*)d_in[2];
    const float* Bp   = (const float*)d_in[3];
    const float* Cp   = (const float*)d_in[4];
    const float* Dp   = (const float*)d_in[5];
    const float* W    = (const float*)d_in[6];
    const float* bo   = (const float*)d_in[7];
    const float* ga   = (const float*)d_in[8];
    const float* be   = (const float*)d_in[9];

    char* ws = (char*)d_ws;
    __hip_bfloat16* Wbf = (__hip_bfloat16*)ws;                   // 512 KiB @ 0
    __hip_bfloat16* xT  = (__hip_bfloat16*)(ws + (3u << 20));    // 8 MiB    @ 3M
    __hip_bfloat16* yT  = (__hip_bfloat16*)(ws + (41u << 20));   // 8 MiB    @ 41M

    k_prep   <<<3072, 256, 0, stream>>>(x, W, xT, Wbf);
    k_ssm    <<<DM, 512, 0, stream>>>(logA, Aim, Bp, Cp, xT, Dp, yT);
    k_gemm_ln<<<(BATCH * SEQ) / 32, 512, 0, stream>>>(yT, Wbf, x, bo, ga, be, (float*)d_out);
}

// Round 27
// 48.430 us; speedup vs baseline: 2.0871x; 1.0015x over previous
//
#include <hip/hip_runtime.h>
#include <hip/hip_bf16.h>
#include <stdint.h>
#include <stddef.h>

#define BATCH 4
#define SEQ   2048
#define DM    512
#define NST   64
#define LN_EPS 1e-5f
#define NCH   32
#define KDIM  192

typedef __attribute__((ext_vector_type(8))) short short8;
typedef __attribute__((ext_vector_type(4))) float f32x4;

__device__ __forceinline__ ushort f2bf(float f) {
    __hip_bfloat16 h = __float2bfloat16(f);
    return *(ushort*)&h;
}
__device__ __forceinline__ float bf2f(ushort u) {
    __hip_bfloat16 h = *(__hip_bfloat16*)&u;
    return __bfloat162float(h);
}

// ---------------- k_prep: x-transpose + W-convert ----------------
__global__ __launch_bounds__(256) void k_prep(
    const float* __restrict__ x, const float* __restrict__ W,
    __hip_bfloat16* __restrict__ xT, __hip_bfloat16* __restrict__ Wbf)
{
    __shared__ float smem[64][33];
    const int tid = threadIdx.x;
    const int bid = blockIdx.x;

    if (bid < 2048) {
        const int dt = bid & 15, lt = (bid >> 4) & 31, b = bid >> 9;
        const int l0 = lt * 64, d0 = dt * 32;
        const int dd = tid & 31, lr = tid >> 5;
        #pragma unroll
        for (int it = 0; it < 8; ++it) {
            int ll = it * 8 + lr;
            smem[ll][dd] = x[((size_t)b * SEQ + l0 + ll) * DM + d0 + dd];
        }
        __syncthreads();
        const int dw = tid >> 3, lg = (tid & 7) * 8;
        ushort pk[8];
        #pragma unroll
        for (int i = 0; i < 8; ++i) pk[i] = f2bf(smem[lg + i][dw]);
        *(short8*)&xT[((size_t)(d0 + dw) * BATCH + b) * SEQ + l0 + lg] = *(short8*)pk;
    } else {
        int i = (bid - 2048) * 256 + tid;
        if (i < DM * DM) Wbf[i] = __float2bfloat16(W[i]);
    }
}

// ---------------- k_ssm v3: 512 threads, in-block G/M build + 3 MFMA phases (round-26 proven) ----------------
__global__ __launch_bounds__(512) void k_ssm(
    const float* __restrict__ logA, const float* __restrict__ Aim,
    const float* __restrict__ Bp, const float* __restrict__ Cp,
    const __hip_bfloat16* __restrict__ xT, const float* __restrict__ Dp,
    __hip_bfloat16* __restrict__ yT)
{
    __shared__ short Zs[128 * 24 * 8];             // 48K: x chunks 0-7, carry chunks 8-23
    __shared__ __align__(16) char Rgn[128 * 129 * 4];   // 64.5K union: Gs / Us / Ms
    __shared__ float Klds[64];
    __shared__ float2 e64s[64];
    short* Gs = (short*)Rgn;
    float (*Us)[129] = (float(*)[129])Rgn;
    short* Ms = (short*)Rgn;

    const int tid = threadIdx.x;
    const int d = blockIdx.x;
    const int w = tid >> 6, lane = tid & 63;
    const int q = lane >> 4, n = lane & 15;

    // ---- issue Zs x-part loads early (land during G build) ----
    short8 xr[2];
    #pragma unroll
    for (int it = 0; it < 2; ++it) {
        int id = it * 512 + tid;
        int col = id >> 3, ck = id & 7;
        int bb = col >> 5, ch = col & 31;
        xr[it] = *(const short8*)&xT[((size_t)d * BATCH + bb) * SEQ + ch * 64 + ck * 8];
    }

    // ---- build G rows (2s,2s+1) chunk w, K partials, carry entries; wave j covers t in [8j,8j+8) ----
    uint mca[8];
    {
        const int s = lane;
        const int i = d * NST + s;
        float aa  = expf(logA[i]);
        float wim = Aim[i];
        float mag = expf(-aa);
        float er = mag * cosf(wim), ei = mag * sinf(wim);
        float Br = Bp[2*i], Bi = Bp[2*i+1];
        float Cr = Cp[2*i], Ci = Cp[2*i+1];
        float CBr = Cr*Br + Ci*Bi;
        float CBi = Cr*Bi - Ci*Br;

        float e2r = er*er - ei*ei,   e2i = 2.f*er*ei;
        float e4r = e2r*e2r - e2i*e2i, e4i = 2.f*e2r*e2i;
        float e8r = e4r*e4r - e4i*e4i, e8i = 2.f*e4r*e4i;       // eA^8
        float ar, ai;
        if (w == 0)      { ar = 1.f;  ai = 0.f; }
        else if (w == 1) { ar = e8r;  ai = e8i; }
        else {
            float e16r = e8r*e8r - e8i*e8i, e16i = 2.f*e8r*e8i;
            if (w == 2)      { ar = e16r; ai = e16i; }
            else if (w == 3) { ar = e16r*e8r - e16i*e8i;  ai = e16r*e8i + e16i*e8r; }
            else {
                float e32r = e16r*e16r - e16i*e16i, e32i = 2.f*e16r*e16i;
                if (w == 4)      { ar = e32r; ai = e32i; }
                else if (w == 5) { ar = e32r*e8r - e32i*e8i;   ai = e32r*e8i + e32i*e8r; }
                else if (w == 6) { ar = e32r*e16r - e32i*e16i; ai = e32r*e16i + e32i*e16r; }
                else {
                    float e48r = e32r*e16r - e32i*e16i, e48i = e32r*e16i + e32i*e16r;
                    ar = e48r*e8r - e48i*e8i;  ai = e48r*e8i + e48i*e8r;   // eA^56
                }
            }
        }
        float prr = CBr*ar - CBi*ai;
        float pii = CBr*ai + CBi*ar;

        float kb[8];
        ushort gR[8], gI[8];
        #pragma unroll
        for (int tt = 0; tt < 8; ++tt) {
            kb[tt] = prr;
            gR[tt] = f2bf(prr);
            gI[tt] = f2bf(pii);
            float npr = er*prr - ei*pii, npi = er*pii + ei*prr;  prr = npr; pii = npi;
            float nar = er*ar - ei*ai,   nai = er*ai + ei*ar;    ar = nar; ai = nai;
            mca[tt] = (uint)f2bf(ar) | ((uint)f2bf(-ai) << 16);
        }
        if (w == 7) e64s[s] = make_float2(ar, ai);

        short8 v;
        int row = 2 * s;
        #pragma unroll
        for (int e = 0; e < 8; ++e) v[e] = (short)gR[e];
        { int cs = w ^ (row & 7); *(short8*)&Gs[(row * 8 + cs) * 8] = v; }
        row = 2 * s + 1;
        #pragma unroll
        for (int e = 0; e < 8; ++e) v[e] = (short)gI[e];
        { int cs = w ^ (row & 7); *(short8*)&Gs[(row * 8 + cs) * 8] = v; }

        #pragma unroll
        for (int tt = 0; tt < 8; ++tt) {
            float v2 = kb[tt];
            #pragma unroll
            for (int mask = 1; mask < 64; mask <<= 1) v2 += __shfl_xor(v2, mask);
            if (lane == 0) Klds[8 * w + tt] = v2;
        }
    }

    // ---- write Zs x-part from prefetched regs ----
    #pragma unroll
    for (int it = 0; it < 2; ++it) {
        int id = it * 512 + tid;
        int col = id >> 3, ck = id & 7;
        int cs = ck ^ (col & 7);
        *(short8*)&Zs[(col * 24 + cs) * 8] = xr[it];
    }
    __syncthreads();

    // ---- phase 1: U = G * X (wave w owns rows 16w..16w+15) ----
    f32x4 acc1[8];
    {
        #pragma unroll
        for (int nf = 0; nf < 8; ++nf)
            #pragma unroll
            for (int k = 0; k < 4; ++k) acc1[nf][k] = 0.f;

        const int arow = w * 16 + n;
        #pragma unroll
        for (int kt = 0; kt < 2; ++kt) {
            int c = kt * 4 + q;
            int csa = c ^ (arow & 7);
            short8 af = *(const short8*)&Gs[(arow * 8 + csa) * 8];
            #pragma unroll
            for (int nf = 0; nf < 8; ++nf) {
                int col = nf * 16 + n;
                int csb = c ^ (col & 7);
                short8 bf = *(const short8*)&Zs[(col * 24 + csb) * 8];
                acc1[nf] = __builtin_amdgcn_mfma_f32_16x16x32_bf16(af, bf, acc1[nf], 0, 0, 0);
            }
        }
    }
    __syncthreads();

    {
        const int r0w = w * 16 + q * 4;
        #pragma unroll
        for (int nf = 0; nf < 8; ++nf) {
            int col = nf * 16 + n;
            #pragma unroll
            for (int r = 0; r < 4; ++r) Us[r0w + r][col] = acc1[nf][r];
        }
    }
    __syncthreads();

    // ---- phase 2: carry combine (tid<256) ----
    if (tid < 256) {
        const int bb = tid >> 6, s = tid & 63;
        const int st = s >> 2, so = (s & 3) * 2;
        float2 a64 = e64s[s];
        const float er = a64.x, ei = a64.y;
        {
            int col = bb * 32 + 31;
            int c = 8 + st, cs = (c & ~7) | ((c & 7) ^ (col & 7));
            *(uint*)&Zs[(col * 24 + cs) * 8 + so] = 0u;
        }
        float gr = Us[2 * s][bb * 32 + 31], gi = Us[2 * s + 1][bb * 32 + 31];
        {
            int col = bb * 32 + 30;
            int c = 8 + st, cs = (c & ~7) | ((c & 7) ^ (col & 7));
            *(uint*)&Zs[(col * 24 + cs) * 8 + so] = (uint)f2bf(gr) | ((uint)f2bf(gi) << 16);
        }
        #pragma unroll 6
        for (int ch = 30; ch >= 1; --ch) {
            float ur = Us[2 * s][bb * 32 + ch], ui = Us[2 * s + 1][bb * 32 + ch];
            float nr = ur + er * gr - ei * gi;
            float ni = ui + er * gi + ei * gr;
            gr = nr; gi = ni;
            int col = bb * 32 + ch - 1;
            int c = 8 + st, cs = (c & ~7) | ((c & 7) ^ (col & 7));
            *(uint*)&Zs[(col * 24 + cs) * 8 + so] = (uint)f2bf(gr) | ((uint)f2bf(gi) << 16);
        }
    }
    __syncthreads();

    // ---- build Ms ----
    {
        {
            int id = tid;
            int row = id >> 3, c = id & 7;
            short8 v;
            #pragma unroll
            for (int e = 0; e < 8; ++e) {
                int col = c * 8 + e;
                float kv = (col >= row) ? Klds[col - row] : 0.f;
                v[e] = (short)f2bf(kv);
            }
            int cs = c ^ (row & 7);
            *(short8*)&Ms[(row * 24 + cs) * 8] = v;
        }
        const int s = lane;
        const int cc = 8 + (s >> 2);
        const int soff = 2 * (s & 3);
        #pragma unroll
        for (int tt = 0; tt < 8; ++tt) {
            int row = 63 - (8 * w + tt);
            int cs = (cc & ~7) | ((cc & 7) ^ (row & 7));
            *(uint*)&Ms[(row * 24 + cs) * 8 + soff] = mca[tt];
        }
    }
    __syncthreads();

    // ---- phase 3: y = M * Z; wave w -> row-tile w>>1, col-half w&1 ----
    f32x4 acc[4];
    #pragma unroll
    for (int nf = 0; nf < 4; ++nf)
        #pragma unroll
        for (int k = 0; k < 4; ++k) acc[nf][k] = 0.f;

    const int arow = (w >> 1) * 16 + n;
    const int nfb  = (w & 1) * 4;
    #pragma unroll
    for (int kt = 0; kt < 6; ++kt) {
        int c = kt * 4 + q;
        int csa = (c & ~7) | ((c & 7) ^ (arow & 7));
        short8 af = *(const short8*)&Ms[(arow * 24 + csa) * 8];
        #pragma unroll
        for (int j = 0; j < 4; ++j) {
            int col = (nfb + j) * 16 + n;
            int csb = (c & ~7) | ((c & 7) ^ (col & 7));
            short8 bfr = *(const short8*)&Zs[(col * 24 + csb) * 8];
            acc[j] = __builtin_amdgcn_mfma_f32_16x16x32_bf16(af, bfr, acc[j], 0, 0, 0);
        }
    }

    const float Dd = Dp[d];
    const int i0 = (w >> 1) * 16 + q * 4;
    #pragma unroll
    for (int j = 0; j < 4; ++j) {
        int col = (nfb + j) * 16 + n;
        int bb = col >> 5, ch = col & 31;
        int cx = (i0 >> 3) ^ (col & 7);
        const ushort* zp = (const ushort*)&Zs[(col * 24 + cx) * 8 + (i0 & 7)];
        ushort o[4];
        #pragma unroll
        for (int r = 0; r < 4; ++r)
            o[r] = f2bf(acc[j][r] + Dd * bf2f(zp[r]));
        *(uint2*)&yT[((size_t)d * BATCH + bb) * SEQ + ch * 64 + i0] = *(uint2*)o;
    }
}

// ---------------- k_gemm_ln v17: double-buffered Bs -> ONE barrier per K-step ----------------
// v14 had 2 barriers/step (31 total) at 1 block/CU: each drain idles all 8 waves.
// v17: write step k+1's W tile into Bs[p^1] while MFMAs read Bs[p] (disjoint); the
// end-of-step barrier publishes p^1. 16 barriers total. LDS 99.6K (1 block/CU).
__global__ __launch_bounds__(512) void k_gemm_ln(
    const __hip_bfloat16* __restrict__ yT, const __hip_bfloat16* __restrict__ Wbf,
    const float* __restrict__ x, const float* __restrict__ bout,
    const float* __restrict__ gamma, const float* __restrict__ beta,
    float* __restrict__ out)
{
    __shared__ short Af[32][520];
    __shared__ short Bs[2][512][32];
    __shared__ float red[8][32][2];
    __shared__ float stats[32][2];

    const int tid  = threadIdx.x;
    const int w    = tid >> 6;
    const int lane = tid & 63;
    const int q    = lane >> 4;
    const int m    = lane & 15;
    const int r0   = blockIdx.x * 32;
    const int bq   = r0 >> 11;
    const int l0   = r0 & 2047;

    // ---- one-time A panel from yT[d][b][l] ----
    {
        const int kdb = tid >> 3, lg = (tid & 7) * 4;
        uint2 u[8];
        #pragma unroll
        for (int j = 0; j < 8; ++j)
            u[j] = *(const uint2*)&yT[((size_t)(j * 64 + kdb) * BATCH + bq) * SEQ + l0 + lg];
        #pragma unroll
        for (int j = 0; j < 8; ++j) {
            int kd = j * 64 + kdb;
            Af[lg + 0][kd] = (short)(u[j].x & 0xffff);
            Af[lg + 1][kd] = (short)(u[j].x >> 16);
            Af[lg + 2][kd] = (short)(u[j].y & 0xffff);
            Af[lg + 3][kd] = (short)(u[j].y >> 16);
        }
    }

    // ---- B tile staging: 512 o x 32 k per step; 4 x 16B per thread ----
    short8 nb0, nb1, nb2, nb3;
    const int ob = tid >> 2, jb = tid & 3;
    const int js = (jb ^ (ob & 3)) * 8;
    #define LOADB(k0) { \
        nb0 = *(const short8*)(Wbf + (size_t)(ob      ) * DM + (k0) + jb * 8); \
        nb1 = *(const short8*)(Wbf + (size_t)(ob + 128) * DM + (k0) + jb * 8); \
        nb2 = *(const short8*)(Wbf + (size_t)(ob + 256) * DM + (k0) + jb * 8); \
        nb3 = *(const short8*)(Wbf + (size_t)(ob + 384) * DM + (k0) + jb * 8); }
    #define WRITEB(p) { \
        *(short8*)&Bs[p][ob      ][js] = nb0; \
        *(short8*)&Bs[p][ob + 128][js] = nb1; \
        *(short8*)&Bs[p][ob + 256][js] = nb2; \
        *(short8*)&Bs[p][ob + 384][js] = nb3; }

    LOADB(0);
    WRITEB(0);
    LOADB(32);
    __syncthreads();

    f32x4 acc[2][4];
    #pragma unroll
    for (int a = 0; a < 2; ++a)
        #pragma unroll
        for (int nn = 0; nn < 4; ++nn)
            #pragma unroll
            for (int k = 0; k < 4; ++k) acc[a][nn][k] = 0.f;

    int p = 0;
    for (int k = 0; k < 16; ++k) {
        if (k < 15) WRITEB(p ^ 1);                // B_{k+1} regs -> other buffer (disjoint from reads)
        if (k < 14) LOADB((k + 2) * 32);          // issue B_{k+2}; lands during MFMAs
        const int k0 = k * 32;
        short8 a0 = *(const short8*)&Af[m][k0 + q * 8];
        short8 a1 = *(const short8*)&Af[16 + m][k0 + q * 8];
        #pragma unroll
        for (int nf = 0; nf < 4; ++nf) {
            int o = w * 64 + nf * 16 + m;         // o&3 == m&3
            short8 bb = *(const short8*)&Bs[p][o][(q ^ (m & 3)) * 8];
            acc[0][nf] = __builtin_amdgcn_mfma_f32_16x16x32_bf16(a0, bb, acc[0][nf], 0, 0, 0);
            acc[1][nf] = __builtin_amdgcn_mfma_f32_16x16x32_bf16(a1, bb, acc[1][nf], 0, 0, 0);
        }
        __syncthreads();                          // publish Bs[p^1]; all reads of Bs[p] done
        p ^= 1;
    }
    #undef LOADB
    #undef WRITEB

    // ---- epilogue: +bias, +x residual, row mean/var, normalize ----
    float bo[4], ga[4], be[4];
    #pragma unroll
    for (int nf = 0; nf < 4; ++nf) {
        int o = w * 64 + nf * 16 + m;
        bo[nf] = bout[o]; ga[nf] = gamma[o]; be[nf] = beta[o];
    }

    float rs[2][4], rq[2][4];
    #pragma unroll
    for (int mf = 0; mf < 2; ++mf)
        #pragma unroll
        for (int i = 0; i < 4; ++i) { rs[mf][i] = 0.f; rq[mf][i] = 0.f; }

    #pragma unroll
    for (int mf = 0; mf < 2; ++mf)
        #pragma unroll
        for (int nf = 0; nf < 4; ++nf) {
            int o = w * 64 + nf * 16 + m;
            #pragma unroll
            for (int i = 0; i < 4; ++i) {
                int row = mf * 16 + q * 4 + i;
                float zv = acc[mf][nf][i] + bo[nf] + x[(size_t)(r0 + row) * DM + o];
                acc[mf][nf][i] = zv;
                rs[mf][i] += zv;
                rq[mf][i] += zv * zv;
            }
        }

    #pragma unroll
    for (int mask = 1; mask < 16; mask <<= 1) {
        #pragma unroll
        for (int mf = 0; mf < 2; ++mf)
            #pragma unroll
            for (int i = 0; i < 4; ++i) {
                rs[mf][i] += __shfl_xor(rs[mf][i], mask);
                rq[mf][i] += __shfl_xor(rq[mf][i], mask);
            }
    }
    if (m == 0) {
        #pragma unroll
        for (int mf = 0; mf < 2; ++mf)
            #pragma unroll
            for (int i = 0; i < 4; ++i) {
                int row = mf * 16 + q * 4 + i;
                red[w][row][0] = rs[mf][i];
                red[w][row][1] = rq[mf][i];
            }
    }
    __syncthreads();
    if (tid < 32) {
        float s = 0.f, sq = 0.f;
        #pragma unroll
        for (int ww = 0; ww < 8; ++ww) { s += red[ww][tid][0]; sq += red[ww][tid][1]; }
        float mu  = s * (1.f / DM);
        float var = sq * (1.f / DM) - mu * mu;
        stats[tid][0] = mu;
        stats[tid][1] = 1.f / sqrtf(var + LN_EPS);
    }
    __syncthreads();

    #pragma unroll
    for (int mf = 0; mf < 2; ++mf)
        #pragma unroll
        for (int i = 0; i < 4; ++i) {
            int row = mf * 16 + q * 4 + i;
            float mu = stats[row][0], rstd = stats[row][1];
            #pragma unroll
            for (int nf = 0; nf < 4; ++nf) {
                int o = w * 64 + nf * 16 + m;
                out[(size_t)(r0 + row) * DM + o] =
                    ga[nf] * (acc[mf][nf][i] - mu) * rstd + be[nf];
            }
        }
}

// ---------------- launcher ----------------
extern "C" void kernel_launch(void* const* d_in, const int* in_sizes, int n_in,
                              void* d_out, int out_size, void* d_ws, size_t ws_size,
                              hipStream_t stream)
{
    const float* x    = (const float*)d_in[0];
    const float* logA = (const float*)d_in[1];
    const float* Aim  = (const float*)d_in[2];
    const float* Bp   = (const float*)d_in[3];
    const float* Cp   = (const float*)d_in[4];
    const float* Dp   = (const float*)d_in[5];
    const float* W    = (const float*)d_in[6];
    const float* bo   = (const float*)d_in[7];
    const float* ga   = (const float*)d_in[8];
    const float* be   = (const float*)d_in[9];

    char* ws = (char*)d_ws;
    __hip_bfloat16* Wbf = (__hip_bfloat16*)ws;                   // 512 KiB @ 0
    __hip_bfloat16* xT  = (__hip_bfloat16*)(ws + (3u << 20));    // 8 MiB    @ 3M
    __hip_bfloat16* yT  = (__hip_bfloat16*)(ws + (41u << 20));   // 8 MiB    @ 41M

    k_prep   <<<3072, 256, 0, stream>>>(x, W, xT, Wbf);
    k_ssm    <<<DM, 512, 0, stream>>>(logA, Aim, Bp, Cp, xT, Dp, yT);
    k_gemm_ln<<<(BATCH * SEQ) / 32, 512, 0, stream>>>(yT, Wbf, x, bo, ga, be, (float*)d_out);
}